// Round 9
// baseline (2114.327 us; speedup 1.0000x reference)
//
#include <hip/hip_runtime.h>

typedef _Float16 h4 __attribute__((ext_vector_type(4)));
typedef float f4 __attribute__((ext_vector_type(4)));

#define SEQ_LEN 50
#define HID 64

#if __has_builtin(__builtin_amdgcn_exp2f)
#define EXP2(x) __builtin_amdgcn_exp2f(x)
#else
extern "C" __device__ float __ocml_native_exp2_f32(float);
#define EXP2(x) __ocml_native_exp2_f32(x)
#endif
#define RCP(x) __builtin_amdgcn_rcpf(x)

// builtin x16 MFMA: compiled AND passed on this harness in R1/R3/R10/R14.
// BUILTINS ONLY (R13 lesson: inline-asm MFMA hides hazards -> NaN).
#define MFMA16(A,B,C) __builtin_amdgcn_mfma_f32_16x16x16f16(A, B, C, 0, 0, 0)

#define LOG2E  1.442695041f
#define LOG2E2 2.885390082f

// R15: R14 core (barrier-free t-loop, reg-resident h, structural weight
// residency) + occupancy 3->4 waves/SIMD + LDS traffic halved.
//
// R14 calibration: tau=3456 cyc/wave-step @3 waves/SIMD, VALUBusy 70% ->
// ~807 busy-cyc/wave-step (trans ~4 cyc issue, not 16). Latency-bound at
// 3 waves; and R14's 65 ds_reads (33KB)/wave-step puts LDS at 90-115 B/cyc
// of a 128-256 B/cyc ceiling at 12 waves/CU -> adding waves requires
// cutting LDS bytes too. Changes:
//  (1) kc=0 AND kc=1 W-chunks in regs (64 VGPRs, both pinned by the
//      R14-proven in-loop empty asm); LDS frag reads 64 -> 32/step.
//  (2) x-proj fragments 8KB -> 1KB: only 2 halves nonzero per (tile,col);
//      packed uint, broadcast b32 read + quad-mask AND + bitcast to h4.
//  (3) x staged as f16 (bext casts to f16 anyway: bit-identical) and
//      final-h buffer aliased into dead sW -> LDS 45.5KB -> 23.3KB.
//  (4) __launch_bounds__(256,4): VGPR ~116 <= 128 -> 4 blocks/CU,
//      16 independent waves/CU (no barrier in the t-loop).
//
// Structure (R10/R14, HW-verified): one wave owns 16 seqs end-to-end.
// mfma_f32_16x16x16_f16 D-layout == B-layout, so the activated h4 of
// unit-quarter dq IS the B-fragment for k-chunk dq of the next step.
//
// Activation math (R6/R7, verified): pre-acts pre-scaled (i,f,o: log2e;
// g: 2log2e, folded into fragments). Cell kept in 2log2e domain. Paired
// rcp both sites. c' clamp 40 keeps paired products finite
// (tanh(40/2L2) = 1-2e-12 == fp32 1.0: no output change).
__global__ __launch_bounds__(256, 4)
void lstm_fused(const float* __restrict__ x,
                const float* __restrict__ W_ih,
                const float* __restrict__ W_hh,
                const float* __restrict__ b_ih,
                const float* __restrict__ b_hh,
                const float* __restrict__ W_fc,
                const float* __restrict__ b_fc,
                float* __restrict__ out)
{
    // sW[tile][s2][lane]: s2=0,1 <-> W_hh k-chunks kc=2,3.  16 KB.
    // Reused as final-h buffer sF (8 KB needed) after the epilogue barrier.
    __shared__ h4       sW[16 * 2 * 64];
    __shared__ _Float16 sXh[SEQ_LEN * 64];   // x transposed [t][seq], f16: 6.4 KB
    __shared__ unsigned sXpk[16 * 16];       // packed x-proj {w,b} per (tile,col): 1 KB

    const int tid  = threadIdx.x;
    const int wave = tid >> 6;
    const int lane = tid & 63;
    const int col  = lane & 15;
    const int quad = lane >> 4;
    const int seqBase = blockIdx.x << 6;     // 64 sequences per block

    // ---- stage x transposed as f16 (cast here == cast at bext: identical)
    for (int i = tid; i < SEQ_LEN * 64; i += 256) {
        const int s = i / SEQ_LEN;
        const int t = i - s * SEQ_LEN;
        sXh[t * 64 + s] = (_Float16)x[(size_t)(seqBase + s) * SEQ_LEN + t];
    }

    // ---- stage kc=2,3 W fragments (pre-scaled; i,f,o: log2e, g: 2log2e)
    for (int i = tid; i < 16 * 2 * 64; i += 256) {
        const int ln   = i & 63;
        const int s2   = (i >> 6) & 1;       // kc = s2 + 2
        const int tile = i >> 7;
        const int gi = tile >> 2, dq = tile & 3;
        const int cl = ln & 15, qd = ln >> 4;
        const int n  = gi * 64 + dq * 16 + cl;
        const float scale = (gi == 2) ? LOG2E2 : LOG2E;
        const float* wp = W_hh + (size_t)n * HID + (s2 + 2) * 16 + qd * 4;
        f4 w = *(const f4*)wp;
        h4 a;
        a[0] = (_Float16)(w[0] * scale);
        a[1] = (_Float16)(w[1] * scale);
        a[2] = (_Float16)(w[2] * scale);
        a[3] = (_Float16)(w[3] * scale);
        sW[i] = a;
    }
    // ---- stage packed x-proj: low half = w_ih*s, high half = bsum*s (RTN)
    if (tid < 256) {
        const int cl = tid & 15, tile = tid >> 4;
        const int gi = tile >> 2, dq = tile & 3;
        const int n  = gi * 64 + dq * 16 + cl;
        const float scale = (gi == 2) ? LOG2E2 : LOG2E;
        union { _Float16 h[2]; unsigned u; } p;
        p.h[0] = (_Float16)(W_ih[n] * scale);
        p.h[1] = (_Float16)((b_ih[n] + b_hh[n]) * scale);
        sXpk[tid] = p.u;
    }

    // ---- kc=0,1 weight chunks resident in registers (64 VGPRs)
    h4 Aw0[4][4], Aw1[4][4];
    #pragma unroll
    for (int gi = 0; gi < 4; ++gi) {
        const float scale = (gi == 2) ? LOG2E2 : LOG2E;
        #pragma unroll
        for (int dq = 0; dq < 4; ++dq) {
            const int n = gi * 64 + dq * 16 + col;
            const float* wp = W_hh + (size_t)n * HID + quad * 4;
            f4 w0 = *(const f4*)wp;
            f4 w1 = *(const f4*)(wp + 16);
            h4 a0, a1;
            a0[0] = (_Float16)(w0[0] * scale); a0[1] = (_Float16)(w0[1] * scale);
            a0[2] = (_Float16)(w0[2] * scale); a0[3] = (_Float16)(w0[3] * scale);
            a1[0] = (_Float16)(w1[0] * scale); a1[1] = (_Float16)(w1[1] * scale);
            a1[2] = (_Float16)(w1[2] * scale); a1[3] = (_Float16)(w1[3] * scale);
            Aw0[gi][dq] = a0;
            Aw1[gi][dq] = a1;
        }
    }

    const f4 z4 = {0.0f, 0.0f, 0.0f, 0.0f};
    const unsigned qmask = (quad == 0) ? 0xFFFFFFFFu : 0u;

    h4 hB[4] = {};          // h as ready-made B-fragments (h0 = 0)
    float c[4][4];
    #pragma unroll
    for (int dq = 0; dq < 4; ++dq)
        #pragma unroll
        for (int r = 0; r < 4; ++r) c[dq][r] = 0.0f;

    __syncthreads();        // staging visible; LAST barrier before epilogue

    #pragma clang loop unroll(disable)
    for (int t = 0; t < SEQ_LEN; ++t) {
        // pin reg-resident chunks: zero-instruction per-iteration redefinition
        // blocks remat (R12 failure) and spill (R10 failure)
        #pragma unroll
        for (int gi = 0; gi < 4; ++gi)
            #pragma unroll
            for (int dq = 0; dq < 4; ++dq) {
                asm volatile("" : "+v"(Aw0[gi][dq]));
                asm volatile("" : "+v"(Aw1[gi][dq]));
            }
        // opaque indices: LDS reads can't be hoisted out of the loop (R12)
        int ob = lane;
        asm volatile("" : "+v"(ob));
        const int obc = ob & 15;

        h4 bext = {};
        bext[0] = sXh[t * 64 + wave * 16 + col];
        bext[1] = (_Float16)1.0f;

        h4 hN[4];
        #pragma unroll
        for (int dq = 0; dq < 4; ++dq) {
            f4 acc[4];
            #pragma unroll
            for (int gi = 0; gi < 4; ++gi) {
                const int tile = gi * 4 + dq;
                // x-proj fragment: broadcast b32 + quad-mask + bitcast
                union { unsigned u2[2]; h4 v; } axc;
                axc.u2[0] = sXpk[tile * 16 + obc] & qmask;
                axc.u2[1] = 0u;
                h4 w2 = sW[(tile * 2 + 0) * 64 + ob];
                h4 w3 = sW[(tile * 2 + 1) * 64 + ob];
                f4 a = MFMA16(axc.v, bext, z4);       // x-term + bias, C=0
                a = MFMA16(Aw0[gi][dq], hB[0], a);
                a = MFMA16(Aw1[gi][dq], hB[1], a);
                a = MFMA16(w2, hB[2], a);
                a = MFMA16(w3, hB[3], a);
                acc[gi] = a;
            }
            // paired-rcp activations (R14 verbatim): 5 exp2 + 1 rcp / unit
            h4 hv;
            #pragma unroll
            for (int rp = 0; rp < 2; ++rp) {
                const int r0 = rp * 2, r1 = r0 + 1;
                float EiA = EXP2(-acc[0][r0]);
                float EfA = EXP2(-acc[1][r0]);
                float EgA = EXP2( acc[2][r0]);
                float EoA = EXP2(-acc[3][r0]);
                float EiB = EXP2(-acc[0][r1]);
                float EfB = EXP2(-acc[1][r1]);
                float EgB = EXP2( acc[2][r1]);
                float EoB = EXP2(-acc[3][r1]);
                float piA = 1.0f + EiA, pfA = 1.0f + EfA;
                float pgA = 1.0f + EgA, poA = 1.0f + EoA;
                float piB = 1.0f + EiB, pfB = 1.0f + EfB;
                float pgB = 1.0f + EgB, poB = 1.0f + EoB;
                float t1A = piA * pgA,  t1B = piB * pgB;
                float DA  = pfA * t1A,  DB  = pfB * t1B;
                float vA  = fmaf(EgA, pfA, -pfA) * LOG2E2;
                float vB  = fmaf(EgB, pfB, -pfB) * LOG2E2;
                float numA = fmaf(c[dq][r0], t1A, vA);
                float numB = fmaf(c[dq][r1], t1B, vB);
                float R   = RCP(DA * DB);
                float cnA = fminf(numA * (R * DB), 40.0f);
                float cnB = fminf(numB * (R * DA), 40.0f);
                c[dq][r0] = cnA;
                c[dq][r1] = cnB;
                float EcA = EXP2(cnA), EcB = EXP2(cnB);
                float DhA = fmaf(poA, EcA, poA);
                float DhB = fmaf(poB, EcB, poB);
                float R2  = RCP(DhA * DhB);
                float rhA = R2 * DhB,  rhB = R2 * DhA;
                hv[r0] = (_Float16)fmaf(EcA, rhA, -rhA);
                hv[r1] = (_Float16)fmaf(EcB, rhB, -rhB);
            }
            hN[dq] = hv;
        }
        #pragma unroll
        for (int dq = 0; dq < 4; ++dq) hB[dq] = hN[dq];
    }

    // ---- epilogue: barrier (all waves done reading sW/sXh), then alias
    // final-h buffer over dead sW. Row stride 64 halves; FC read staggered
    // per-lane to dodge the same-bank row starts.
    __syncthreads();
    _Float16* sF = (_Float16*)sW;
    #pragma unroll
    for (int dq = 0; dq < 4; ++dq)
        *(h4*)(sF + (wave * 16 + col) * HID + dq * 16 + quad * 4) = hB[dq];
    // FC readback is wave-local (own 16 rows): compiler orders ds_write ->
    // ds_read within the wave; no further barrier needed.

    if (lane < 48) {
        const int sl = lane / 3;   // sequence within this wave's 16
        const int nc = lane % 3;   // class
        const _Float16* hp = sF + (wave * 16 + sl) * HID;
        float a = b_fc[nc];
        const int u0 = (sl * 4) & 63;
        #pragma unroll
        for (int k = 0; k < HID; ++k) {
            const int u = (u0 + k) & 63;
            a = fmaf((float)hp[u], W_fc[nc * HID + u], a);
        }
        out[(size_t)(seqBase + wave * 16 + sl) * 3 + nc] = a;
    }
}

extern "C" void kernel_launch(void* const* d_in, const int* in_sizes, int n_in,
                              void* d_out, int out_size, void* d_ws, size_t ws_size,
                              hipStream_t stream) {
    const float* x    = (const float*)d_in[0];
    const float* W_ih = (const float*)d_in[1];
    const float* W_hh = (const float*)d_in[2];
    const float* b_ih = (const float*)d_in[3];
    const float* b_hh = (const float*)d_in[4];
    const float* W_fc = (const float*)d_in[5];
    const float* b_fc = (const float*)d_in[6];
    float* out = (float*)d_out;

    const int nSeq   = in_sizes[0] / SEQ_LEN;  // 512000
    const int blocks = nSeq / 64;              // 8000

    hipLaunchKernelGGL(lstm_fused, dim3(blocks), dim3(256), 0, stream,
                       x, W_ih, W_hh, b_ih, b_hh, W_fc, b_fc, out);
}

// Round 10
// 1600.642 us; speedup vs baseline: 1.3209x; 1.3209x over previous
//
#include <hip/hip_runtime.h>

typedef _Float16 h8 __attribute__((ext_vector_type(8)));
typedef _Float16 h4 __attribute__((ext_vector_type(4)));
typedef float f4 __attribute__((ext_vector_type(4)));
typedef float f2 __attribute__((ext_vector_type(2)));

#define SEQ_LEN 50
#define HID 64
#define HS 72  // halves per h row: 144B pitch; 16B-aligned b128 reads

#if __has_builtin(__builtin_amdgcn_exp2f)
#define EXP2(x) __builtin_amdgcn_exp2f(x)
#else
extern "C" __device__ float __ocml_native_exp2_f32(float);
#define EXP2(x) __ocml_native_exp2_f32(x)
#endif
#define RCP(x) __builtin_amdgcn_rcpf(x)

#if __has_builtin(__builtin_amdgcn_mfma_f32_16x16x16f16)
typedef h4 axv_t;
#define XMFMA(A,B,C) __builtin_amdgcn_mfma_f32_16x16x16f16(A, B, C, 0, 0, 0)
#else
typedef h8 axv_t;
#define XMFMA(A,B,C) __builtin_amdgcn_mfma_f32_16x16x32_f16(A, B, C, 0, 0, 0)
#endif
#define WMFMA(A,B,C) __builtin_amdgcn_mfma_f32_16x16x32_f16(A, B, C, 0, 0, 0)

#define LOG2E  1.442695041f
#define LOG2E2 2.885390082f

// R16 = R1 champion kernel (1752us) + packed-f32 activation math.
//
// Issue-port model (fits R1..R15): R1's wave-step issues ~520 cyc
// (trans 48x4, activation VALU ~208x2-equiv, MFMA ~48, misc ~70) x 2.65
// resident waves ~= wall 1490 -> SIMD issue ~90% saturated. Explains why
// issue-neutral restructures (R3 2-tile, R14 barrier-free, R15 occupancy)
// were flat-to-worse and why only instruction-count cuts can win.
//
// Change: the A/B-paired activation block is expressed on float2
// ext-vectors so clang lowers to v_pk_add_f32 / v_pk_mul_f32 /
// v_pk_fma_f32 (gfx90a+ VOP3P dual-f32): one issue slot per two scalar
// ops -> activation VALU (~40% of issue) halves. Trans stays f32 scalar
// (range requires f32; no pk trans exists). Everything else is R1
// verbatim: 2-wave block, 16 seqs, x32 MFMAs, LDS h double-buffer,
// one barrier per step.
//
// Activation math (R6/R7, verified): pre-acts pre-scaled (i,f,o: log2e;
// g: 2log2e, folded into A). Cell kept in 2log2e domain. Paired rcp both
// sites (R=rcp(Da*Db); 1/Da=R*Db). c' clamp 40 keeps paired products
// finite (tanh(40/2L2)=1-2e-12 == fp32 1.0: no output change).
__global__ __launch_bounds__(128, 3)
void lstm_fused(const float* __restrict__ x,
                const float* __restrict__ W_ih,
                const float* __restrict__ W_hh,
                const float* __restrict__ b_ih,
                const float* __restrict__ b_hh,
                const float* __restrict__ W_fc,
                const float* __restrict__ b_fc,
                float* __restrict__ out)
{
    __shared__ _Float16 sH[2][16 * HS];    // h double-buffer: h[seq][unit], fp16
    __shared__ float    sXT[SEQ_LEN * 16]; // x tile, transposed [t][seq]

    const int tid  = threadIdx.x;
    const int wave = tid >> 6;
    const int lane = tid & 63;
    const int col  = lane & 15;
    const int quad = lane >> 4;
    const int seqBase = blockIdx.x << 4;

    // ---- stage x transposed: sXT[t*16 + s] = x[(seqBase+s)*50 + t]
    for (int i = tid; i < SEQ_LEN * 16; i += 128) {
        const int s = i & 15;
        const int t = i >> 4;
        sXT[t * 16 + s] = x[(size_t)(seqBase + s) * SEQ_LEN + t];
    }
    // ---- zero both h buffers (h0 = 0)
    for (int i = tid; i < 2 * 16 * HS; i += 128)
        ((_Float16*)sH)[i] = (_Float16)0.0f;

    // ---- W_hh rows as resident fp16 A-fragments, pre-scaled (i,f,o: log2e;
    // g: 2log2e). A[m=col][k=quad*8+j] = W[unit][kf*32+quad*8+j].
    h8 Aw[8][2];
    axv_t Ax[8];
    #pragma unroll
    for (int gi = 0; gi < 4; ++gi) {
        const float scale = (gi == 2) ? LOG2E2 : LOG2E;
        #pragma unroll
        for (int d = 0; d < 2; ++d) {
            const int tt = gi * 2 + d;
            const int n  = (gi * 4 + 2 * wave + d) * 16 + col;
            axv_t axf = {};
            if (quad == 0) {
                axf[0] = (_Float16)(W_ih[n] * scale);
                axf[1] = (_Float16)((b_ih[n] + b_hh[n]) * scale);
            }
            Ax[tt] = axf;
            #pragma unroll
            for (int kf = 0; kf < 2; ++kf) {
                const float* wp = W_hh + n * HID + kf * 32 + quad * 8;
                f4 lo = *(const f4*)wp;
                f4 hi = *(const f4*)(wp + 4);
                h8 b;
                b[0] = (_Float16)(lo[0] * scale); b[1] = (_Float16)(lo[1] * scale);
                b[2] = (_Float16)(lo[2] * scale); b[3] = (_Float16)(lo[3] * scale);
                b[4] = (_Float16)(hi[0] * scale); b[5] = (_Float16)(hi[1] * scale);
                b[6] = (_Float16)(hi[2] * scale); b[7] = (_Float16)(hi[3] * scale);
                Aw[tt][kf] = b;
            }
        }
    }

    const f4 z4 = {0.0f, 0.0f, 0.0f, 0.0f};

    // cell state (2log2e domain), as f2 pairs: [d][rp]
    f2 c2[2][2];
    #pragma unroll
    for (int d = 0; d < 2; ++d)
        #pragma unroll
        for (int rp = 0; rp < 2; ++rp) c2[d][rp] = (f2){0.0f, 0.0f};

    __syncthreads();

    #pragma unroll 2
    for (int t = 0; t < SEQ_LEN; ++t) {
        const _Float16* hb = sH[t & 1];
        _Float16*       hw = sH[(t + 1) & 1];

        // B_x = {x_t[seq], 1, ...}: only k=0,1 (quad0 lanes of A_x) matter.
        const float xt = sXT[t * 16 + col];
        axv_t bx = {};
        bx[0] = (_Float16)xt;
        bx[1] = (_Float16)1.0f;

        // B = h^T fragments: B[k=quad*8+j][n=col] = h[col][kf*32+quad*8+j]
        const h8 Bh0 = *(const h8*)(hb + col * HS + quad * 8);
        const h8 Bh1 = *(const h8*)(hb + col * HS + 32 + quad * 8);

        // Two d-groups: 4 live accumulators each (i,f,g,o of the same units)
        #pragma unroll
        for (int d = 0; d < 2; ++d) {
            f4 acc[4];
            #pragma unroll
            for (int gi = 0; gi < 4; ++gi) {
                const int tt = gi * 2 + d;
                f4 a = XMFMA(Ax[tt], bx, z4);
                a = WMFMA(Aw[tt][0], Bh0, a);
                a = WMFMA(Aw[tt][1], Bh1, a);
                acc[gi] = a;
            }
            // packed-f32 paired activations: 6 trans + ~20 pk-VALU per pair
            h4 hv;
            #pragma unroll
            for (int rp = 0; rp < 2; ++rp) {
                const int r0 = rp * 2, r1 = r0 + 1;
                f2 Ei = { EXP2(-acc[0][r0]), EXP2(-acc[0][r1]) };
                f2 Ef = { EXP2(-acc[1][r0]), EXP2(-acc[1][r1]) };
                f2 Eg = { EXP2( acc[2][r0]), EXP2( acc[2][r1]) };
                f2 Eo = { EXP2(-acc[3][r0]), EXP2(-acc[3][r1]) };
                f2 pi = 1.0f + Ei;                 // v_pk_add_f32
                f2 pf = 1.0f + Ef;
                f2 pg = 1.0f + Eg;
                f2 po = 1.0f + Eo;
                f2 t1 = pi * pg;                   // v_pk_mul_f32
                f2 D  = pf * t1;
                f2 v  = (Eg * pf - pf) * LOG2E2;   // pk_fma + pk_mul
                f2 num = c2[d][rp] * t1 + v;       // v_pk_fma_f32
                float R = RCP(D[0] * D[1]);        // shared rcp #1
                f2 Dsw = { D[1], D[0] };
                f2 cn  = (num * Dsw) * R;          // pk_mul + pk_mul(bcast)
                cn[0] = fminf(cn[0], 40.0f);       // overflow guard
                cn[1] = fminf(cn[1], 40.0f);
                c2[d][rp] = cn;
                f2 Ec = { EXP2(cn[0]), EXP2(cn[1]) };
                f2 Dh = po * Ec + po;              // v_pk_fma_f32
                float R2 = RCP(Dh[0] * Dh[1]);     // shared rcp #2
                f2 Dhsw = { Dh[1], Dh[0] };
                f2 rh = R2 * Dhsw;                 // pk_mul(bcast)
                f2 hvf = Ec * rh - rh;             // v_pk_fma_f32
                hv[r0] = (_Float16)hvf[0];
                hv[r1] = (_Float16)hvf[1];
            }
            *(h4*)(hw + col * HS + 32 * wave + 16 * d + quad * 4) = hv;
        }
        __syncthreads();
    }

    // ---- epilogue: final h in sH[0], layout h[seq][unit] stride HS
    if (lane < 24) {
        const int sl = wave * 8 + lane / 3;  // sequence within tile
        const int nc = lane % 3;             // class
        const _Float16* hp = sH[0] + sl * HS;
        float a = b_fc[nc];
        #pragma unroll
        for (int u = 0; u < HID; ++u)
            a = fmaf((float)hp[u], W_fc[nc * HID + u], a);
        out[(size_t)(seqBase + sl) * 3 + nc] = a;
    }
}

extern "C" void kernel_launch(void* const* d_in, const int* in_sizes, int n_in,
                              void* d_out, int out_size, void* d_ws, size_t ws_size,
                              hipStream_t stream) {
    const float* x    = (const float*)d_in[0];
    const float* W_ih = (const float*)d_in[1];
    const float* W_hh = (const float*)d_in[2];
    const float* b_ih = (const float*)d_in[3];
    const float* b_hh = (const float*)d_in[4];
    const float* W_fc = (const float*)d_in[5];
    const float* b_fc = (const float*)d_in[6];
    float* out = (float*)d_out;

    const int nSeq   = in_sizes[0] / SEQ_LEN;  // 512000
    const int blocks = nSeq / 16;              // 32000

    hipLaunchKernelGGL(lstm_fused, dim3(blocks), dim3(128), 0, stream,
                       x, W_ih, W_hh, b_ih, b_hh, W_fc, b_fc, out);
}